// Round 36
// baseline (203.432 us; speedup 1.0000x reference)
//
#include <hip/hip_runtime.h>
#include <hip/hip_bf16.h>
#include <math.h>

#define BD 8
#define HH 56
#define WW 56
#define CC 384
#define HEADS 12
#define HD 32
#define WS 7
#define SS 3
#define NTOK 49
#define NWIN 64            // windows per image (8x8)
#define TOKENS (BD*HH*WW)  // 25088
#define HID 1536
#define TPI (HH*WW)        // tokens per image: 3136

typedef __attribute__((ext_vector_type(8))) short bf16x8;
typedef __attribute__((ext_vector_type(4))) float f32x4;

__device__ __forceinline__ unsigned short f2bf(float f) {
    unsigned int u = __float_as_uint(f);
    unsigned int r = (u + 0x7FFFu + ((u >> 16) & 1u)) >> 16;
    return (unsigned short)r;
}
// 1-op RNE f32->bf16 via packed convert (low half); bitwise-identical to f2bf.
__device__ __forceinline__ unsigned short f2bf_fast(float v) {
    unsigned int w;
    asm("v_cvt_pk_bf16_f32 %0, %1, %2" : "=v"(w) : "v"(v), "v"(v));
    return (unsigned short)w;
}
// pack two f32 -> u32 of 2 bf16 (lo = first arg)
__device__ __forceinline__ unsigned int pk2bf(float lo, float hi) {
    unsigned int w;
    asm("v_cvt_pk_bf16_f32 %0, %1, %2" : "=v"(w) : "v"(lo), "v"(hi));
    return w;
}
__device__ __forceinline__ float bf2f(unsigned short h) {
    return __uint_as_float(((unsigned int)h) << 16);
}
__device__ __forceinline__ void gload16(const void* g, void* l) {
    __builtin_amdgcn_global_load_lds((const __attribute__((address_space(1))) unsigned int*)g,
                                     (__attribute__((address_space(3))) unsigned int*)l, 16, 0, 0);
}
// tanh-form GELU via exp2 + hw rcp: ~9 VALU ops, |err vs exact erf-GELU| <= ~3e-4 abs.
__device__ __forceinline__ float fgelu(float x) {
    float x2 = x * x;
    float y  = x * fmaf(0.03567740814f, x2, 0.7978845608f);  // sqrt(2/pi)*(x + 0.044715 x^3)
    float e  = exp2f(y * 2.8853900818f);                     // e^{2y}
    float r  = __builtin_amdgcn_rcpf(e + 1.0f);
    return x - x * r;                                        // 0.5x(1+tanh y)
}
// bijective XCD-aware block swizzle (m204 form)
__device__ __forceinline__ int xcd_swz(int lid, int nwg) {
    int xcd = lid & 7, pos = lid >> 3;
    int q = nwg >> 3, r = nwg & 7;
    return (xcd < r ? xcd * (q + 1) : r * (q + 1) + (xcd - r) * q) + pos;
}

// ---------------- device bodies for the fused prep kernel ----------------
// W[K][N] fp32 -> Wt[N][K] bf16 (32x32 transpose tile)
__device__ __forceinline__ void dev_wprep(const float* __restrict__ W, unsigned short* __restrict__ Th,
                                          int K, int N, int bx, int by, int tid, float (*t)[33])
{
    int n0 = bx * 32, k0 = by * 32;
    int c = tid & 31, r = tid >> 5;   // r: 0..7
    #pragma unroll
    for (int rr = 0; rr < 32; rr += 8)
        t[r + rr][c] = W[(size_t)(k0 + r + rr) * N + n0 + c];
    __syncthreads();
    #pragma unroll
    for (int rr = 0; rr < 32; rr += 8) {
        int i = r + rr;                 // n-local
        Th[(size_t)(n0 + i) * K + k0 + c] = f2bf(t[c][i]);
    }
}

// bias table element e: [4 wtype][12 head][64x64] in MFMA acc layout, pre-scaled
__device__ __forceinline__ void dev_bias(const float* __restrict__ rpb, float* __restrict__ Bias, int e)
{
    int wtq = e / 49152;
    int hr  = e - wtq * 49152;
    int h   = hr >> 12;
    int rem = hr & 4095;
    int jt = rem >> 10, it = (rem >> 8) & 3, lane = (rem >> 2) & 63, reg = rem & 3;
    int j = jt * 16 + ((lane >> 4) << 2) + reg;   // S^T row (= k token)
    int i = it * 16 + (lane & 15);                // S^T col (= q token)
    float val;
    if (j >= NTOK) val = -1e30f;                  // pad columns -> p = 0
    else if (i >= NTOK) val = 0.0f;               // pad q rows, unused
    else {
        int ti = i / 7, tj = i - ti * 7, yj = j / 7, xj = j - yj * 7;
        float b = rpb[((ti - yj + 6) * 13 + (tj - xj + 6)) * HEADS + h];
        int wh7 = wtq >> 1, ww7 = wtq & 1;
        int lhi = wh7 ? (ti < 4 ? 1 : 2) : 0, lhj = wh7 ? (yj < 4 ? 1 : 2) : 0;
        int lwi = ww7 ? (tj < 4 ? 1 : 2) : 0, lwj = ww7 ? (xj < 4 ? 1 : 2) : 0;
        if (lhi != lhj || lwi != lwj) b -= 100.0f;
        val = b * 5.65685424949238f;              // / scale  (scale = 1/sqrt(32))
    }
    Bias[e] = val;
}

// LN row m (shift+window gather), one wave per row: lane owns 6 contiguous elems.
template<bool SHIFT>
__device__ __forceinline__ void dev_ln(const float* __restrict__ in, const float* __restrict__ g,
                                       const float* __restrict__ beta, unsigned short* __restrict__ oh,
                                       int m, int lane)
{
    const float* src;
    size_t dbase = (size_t)m * CC;
    if (SHIFT) {
        int b  = m / (NWIN * NTOK);
        int rr = m % (NWIN * NTOK);
        int w  = rr / NTOK;
        int t  = rr % NTOK;
        int wh = w >> 3, ww = w & 7;
        int ti = t / 7,  tj = t - (t / 7) * 7;
        int hh = wh * WS + ti + SS;  if (hh >= HH) hh -= HH;
        int w2 = ww * WS + tj + SS;  if (w2 >= WW) w2 -= WW;
        src = in + ((size_t)b * TPI + hh * WW + w2) * CC;
    } else {
        src = in + (size_t)m * CC;
    }
    int e0 = lane * 6;
    float2 a  = *(const float2*)(src + e0);
    float2 b2 = *(const float2*)(src + e0 + 2);
    float2 c2 = *(const float2*)(src + e0 + 4);
    float s  = (a.x + a.y) + (b2.x + b2.y) + (c2.x + c2.y);
    float ss = a.x*a.x + a.y*a.y + b2.x*b2.x + b2.y*b2.y + c2.x*c2.x + c2.y*c2.y;
    #pragma unroll
    for (int off = 1; off < 64; off <<= 1) {
        s  += __shfl_xor(s, off);
        ss += __shfl_xor(ss, off);
    }
    float mu   = s * (1.0f / CC);
    float var  = ss * (1.0f / CC) - mu * mu;
    float rstd = rsqrtf(var + 1e-5f);
    float2 ga = *(const float2*)(g + e0);
    float2 gb = *(const float2*)(g + e0 + 2);
    float2 gc = *(const float2*)(g + e0 + 4);
    float2 ba = *(const float2*)(beta + e0);
    float2 bb = *(const float2*)(beta + e0 + 2);
    float2 bc = *(const float2*)(beta + e0 + 4);
    float y0 = (a.x  - mu) * rstd * ga.x + ba.x;
    float y1 = (a.y  - mu) * rstd * ga.y + ba.y;
    float y2 = (b2.x - mu) * rstd * gb.x + bb.x;
    float y3 = (b2.y - mu) * rstd * gb.y + bb.y;
    float y4 = (c2.x - mu) * rstd * gc.x + bc.x;
    float y5 = (c2.y - mu) * rstd * gc.y + bc.y;
    unsigned short* orow = oh + dbase + e0;
    *(unsigned int*)(orow)     = pk2bf(y0, y1);
    *(unsigned int*)(orow + 2) = pk2bf(y2, y3);
    *(unsigned int*)(orow + 4) = pk2bf(y4, y5);
}

// ---------------- fused prep: bias table + 4 weight transposes + LN1 (all independent) ------
// blocks [0,768) bias | [768,1200) Wq | [1200,1344) Wp | [1344,1920) W1 | [1920,2496) W2 |
// [2496,8768) LN1 (4 rows/block)
__global__ __launch_bounds__(256)
void prep_all(const float* __restrict__ rpb, float* __restrict__ Bias,
              const float* __restrict__ qkv_w, unsigned short* __restrict__ Wqh,
              const float* __restrict__ proj_w, unsigned short* __restrict__ Wph,
              const float* __restrict__ fc1w, unsigned short* __restrict__ W1h,
              const float* __restrict__ fc2w, unsigned short* __restrict__ W2h,
              const float* __restrict__ x, const float* __restrict__ n1g,
              const float* __restrict__ n1b, unsigned short* __restrict__ ABh)
{
    __shared__ float t[32][33];
    int b = blockIdx.x, tid = threadIdx.x;
    if (b < 768) {
        dev_bias(rpb, Bias, b * 256 + tid);
    } else if (b < 1200) {
        int id = b - 768;  dev_wprep(qkv_w,  Wqh, 384, 1152, id % 36, id / 36, tid, t);
    } else if (b < 1344) {
        int id = b - 1200; dev_wprep(proj_w, Wph, 384,  384, id % 12, id / 12, tid, t);
    } else if (b < 1920) {
        int id = b - 1344; dev_wprep(fc1w,   W1h, 384, 1536, id % 48, id / 48, tid, t);
    } else if (b < 2496) {
        int id = b - 1920; dev_wprep(fc2w,   W2h, 1536, 384, id % 12, id / 12, tid, t);
    } else {
        int m = (b - 2496) * 4 + (tid >> 6);
        dev_ln<true>(x, n1g, n1b, ABh, m, tid & 63);
    }
}

// ---------------- standalone LN (ln2, no shift): 1 wave/row, 4 rows/block ----------------
__global__ __launch_bounds__(256)
void ln2_kernel(const float* __restrict__ in, const float* __restrict__ g,
                const float* __restrict__ beta, unsigned short* __restrict__ oh)
{
    int m = blockIdx.x * 4 + (threadIdx.x >> 6);
    dev_ln<false>(in, g, beta, oh, m, threadIdx.x & 63);
}

// ================ epilogue types ================
#define EPI_QKV  0   // outh = bf16(acc + bias)  -> QKVb [tok][1152] coalesced
#define EPI_GELU 1   // outh = bf16(gelu(acc + bias))           (fc1)
#define EPI_PROJ 2   // outf[pix] = extra[pix] + acc + bias     (proj + window-reverse + roll + residual)
#define EPI_FC2  3   // outf = extra + acc + bias               (fc2 + residual)

// ---------------- 1-pass bf16 MFMA GEMM: 128x128 tile, BK=32, 4 WAVES x (64x64 each) -------
// m97 shape: per-wave 64x64 -> 32.8 FLOP per LDS-read-byte; VALUBusy ~12% (r35 measured).
// 3-buffer, prefetch-distance-2 counted-vmcnt pipeline (validated r26/r27), scaled to
// 4 loads/wave/tile -> steady vmcnt(8), tails 4/0. LDS 48 KB -> 3 blocks x 4 waves = 12 w/CU.
#define COMPUTE128(B) do {                                                          \
    bf16x8 ah[4], bh[4];                                                            \
    _Pragma("unroll")                                                               \
    for (int f = 0; f < 4; ++f) {                                                   \
        int row = wr * 64 + f * 16 + rA;                                            \
        int pp = (kslot ^ ((row >> 1) & 3)) * 8;                                    \
        ah[f] = *(const bf16x8*)&lds[B][0][row][pp];                                \
        int col = wc * 64 + f * 16 + rA;                                            \
        int pb = (kslot ^ ((col >> 1) & 3)) * 8;                                    \
        bh[f] = *(const bf16x8*)&lds[B][1][col][pb];                                \
    }                                                                               \
    _Pragma("unroll")                                                               \
    for (int i = 0; i < 4; ++i)                                                     \
        _Pragma("unroll")                                                           \
        for (int j = 0; j < 4; ++j)                                                 \
            acc[i][j] = __builtin_amdgcn_mfma_f32_16x16x32_bf16(ah[i], bh[j], acc[i][j], 0, 0, 0); \
} while (0)

template<int EPI>
__global__ __launch_bounds__(256)
void gemm_mfma(const unsigned short* __restrict__ Ah, const unsigned short* __restrict__ Bh,
               const float* __restrict__ bias, const float* __restrict__ extra,
               float* __restrict__ outf, unsigned short* __restrict__ outh,
               int M, int N, int K)
{
    __shared__ unsigned short lds[3][2][128][32];   // [buf][A/B][row][k], 48 KB

    int nwg = gridDim.x * gridDim.y;
    int wid = xcd_swz(blockIdx.y * gridDim.x + blockIdx.x, nwg);
    int nblk = wid % gridDim.x;
    int mblk = wid / gridDim.x;

    int tid  = threadIdx.x;
    int lane = tid & 63;
    int wave = tid >> 6;       // 0..3
    int wr = wave >> 1;        // 0..1 (M half)
    int wc = wave & 1;         // 0..1 (N half)
    int m0 = mblk * 128, n0 = nblk * 128;

    int lrow = lane >> 2;      // staging row within 16-row chunk
    int ps   = lane & 3;       // staging 16B slot
    int kslot = lane >> 4;     // frag k-chunk
    int rA    = lane & 15;     // frag row/col

    // hoisted loop-invariant staging addresses (4 segs, 3 buffer dests each)
    const unsigned short* gsrc[4];
    unsigned short* d0[4];
    unsigned short* d1[4];
    unsigned short* d2[4];
    #pragma unroll
    for (int s = 0; s < 4; ++s) {
        int seg = wave * 4 + s;          // 0..15: 0-7 A, 8-15 Bh
        int bf = seg >> 3, c = seg & 7;
        const unsigned short* gb = (bf == 0) ? Ah : Bh;
        int r0 = (bf == 0) ? m0 : n0;
        int row = c * 16 + lrow;
        int ks = ps ^ ((row >> 1) & 3);
        gsrc[s] = gb + (size_t)(r0 + row) * K + ks * 8;
        d0[s] = &lds[0][bf][c * 16][0];
        d1[s] = &lds[1][bf][c * 16][0];
        d2[s] = &lds[2][bf][c * 16][0];
    }

    f32x4 acc[4][4];
    #pragma unroll
    for (int i = 0; i < 4; ++i)
        #pragma unroll
        for (int j = 0; j < 4; ++j)
            acc[i][j] = (f32x4){0.f, 0.f, 0.f, 0.f};

    const int nt = K / 32;     // 12 (qkv/fc1/proj) or 48 (fc2); both % 3 == 0
    // prologue: tiles 0,1 -> buf0,buf1 (8 loads outstanding)
    #pragma unroll
    for (int s = 0; s < 4; ++s) gload16(gsrc[s], d0[s]);
    #pragma unroll
    for (int s = 0; s < 4; ++s) gload16(gsrc[s] + 32, d1[s]);
    for (int t = 0; t < nt; t += 3) {
        // phase A: prefetch t+2 -> buf2, wait tile t, compute buf0
        if (t + 2 < nt) {
            int ka = (t + 2) * 32;
            #pragma unroll
            for (int s = 0; s < 4; ++s) gload16(gsrc[s] + ka, d2[s]);
            asm volatile("s_waitcnt vmcnt(8)" ::: "memory");
        } else if (t + 1 < nt) {
            asm volatile("s_waitcnt vmcnt(4)" ::: "memory");
        } else {
            asm volatile("s_waitcnt vmcnt(0)" ::: "memory");
        }
        __builtin_amdgcn_sched_barrier(0);
        __builtin_amdgcn_s_barrier();
        __builtin_amdgcn_sched_barrier(0);
        COMPUTE128(0);
        __builtin_amdgcn_s_barrier();
        // phase B: prefetch t+3 -> buf0, wait tile t+1, compute buf1
        if (t + 3 < nt) {
            int kb = (t + 3) * 32;
            #pragma unroll
            for (int s = 0; s < 4; ++s) gload16(gsrc[s] + kb, d0[s]);
            asm volatile("s_waitcnt vmcnt(8)" ::: "memory");
        } else if (t + 2 < nt) {
            asm volatile("s_waitcnt vmcnt(4)" ::: "memory");
        } else {
            asm volatile("s_waitcnt vmcnt(0)" ::: "memory");
        }
        __builtin_amdgcn_sched_barrier(0);
        __builtin_amdgcn_s_barrier();
        __builtin_amdgcn_sched_barrier(0);
        COMPUTE128(1);
        __builtin_amdgcn_s_barrier();
        // phase C: prefetch t+4 -> buf1, wait tile t+2, compute buf2
        if (t + 4 < nt) {
            int kc = (t + 4) * 32;
            #pragma unroll
            for (int s = 0; s < 4; ++s) gload16(gsrc[s] + kc, d1[s]);
            asm volatile("s_waitcnt vmcnt(8)" ::: "memory");
        } else if (t + 3 < nt) {
            asm volatile("s_waitcnt vmcnt(4)" ::: "memory");
        } else {
            asm volatile("s_waitcnt vmcnt(0)" ::: "memory");
        }
        __builtin_amdgcn_sched_barrier(0);
        __builtin_amdgcn_s_barrier();
        __builtin_amdgcn_sched_barrier(0);
        COMPUTE128(2);
        __builtin_amdgcn_s_barrier();
    }

    int cn = lane & 15;
    int rb = (lane >> 4) * 4;
    float bj[4];
    #pragma unroll
    for (int j = 0; j < 4; ++j) bj[j] = bias[n0 + wc * 64 + j * 16 + cn];
    int ncol = n0 + wc * 64 + cn;

    #pragma unroll
    for (int i = 0; i < 4; ++i) {
        #pragma unroll
        for (int r = 0; r < 4; ++r) {
            int mg = m0 + wr * 64 + i * 16 + rb + r;
            if (EPI == EPI_QKV) {
                unsigned short* orow = outh + (size_t)mg * N + ncol;
                #pragma unroll
                for (int j = 0; j < 4; ++j) orow[j * 16] = f2bf_fast(acc[i][j][r] + bj[j]);
            } else if (EPI == EPI_GELU) {
                unsigned short* orow = outh + (size_t)mg * N + ncol;
                #pragma unroll
                for (int j = 0; j < 4; ++j)
                    orow[j * 16] = f2bf_fast(fgelu(acc[i][j][r] + bj[j]));
            } else if (EPI == EPI_PROJ) {
                int b  = mg / (NWIN * NTOK);
                int rr = mg % (NWIN * NTOK);
                int w  = rr / NTOK;
                int t  = rr % NTOK;
                int wh = w >> 3, ww = w & 7;
                int ti = t / 7,  tj = t - (t / 7) * 7;
                int hh = wh * WS + ti + SS;  if (hh >= HH) hh -= HH;
                int w2 = ww * WS + tj + SS;  if (w2 >= WW) w2 -= WW;
                size_t pix = (size_t)b * TPI + hh * WW + w2;
                const float* xin = extra + pix * CC + ncol;
                float* xo = outf + pix * CC + ncol;
                #pragma unroll
                for (int j = 0; j < 4; ++j) xo[j * 16] = xin[j * 16] + acc[i][j][r] + bj[j];
            } else { // EPI_FC2
                const float* xi = extra + (size_t)mg * N + ncol;
                float* xo = outf + (size_t)mg * N + ncol;
                #pragma unroll
                for (int j = 0; j < 4; ++j) xo[j * 16] = xi[j * 16] + acc[i][j][r] + bj[j];
            }
        }
    }
}

// ---------------- Attention v4: MFMA, one wave per (window, head), LDS V-transpose ----------
__global__ __launch_bounds__(256)
void attn3(const unsigned short* __restrict__ QKVb, const float* __restrict__ Bias,
           unsigned short* __restrict__ outh, int win0)
{
    int wave = threadIdx.x >> 6, lane = threadIdx.x & 63;
    int unit = blockIdx.x * 4 + wave;
    int head = unit % HEADS;
    int winl = unit / HEADS;
    int wing = win0 + winl;
    int wl   = wing & (NWIN - 1);
    int wt   = (((wl >> 3) == 7) << 1) | ((wl & 7) == 7);
    int qbase = winl * NTOK;
    size_t obase = (size_t)wing * NTOK;

    __shared__ __align__(16) unsigned short Pl_all[4][64][64];
    __shared__ __align__(16) unsigned short Vt_all[4][2048];   // [32 d][8 blk of 8 tok], XOR-swizzled
    unsigned short (*Pl)[64] = Pl_all[wave];
    unsigned short* Vt = Vt_all[wave];

    int l15 = lane & 15, g = lane >> 4;

    // ---- zero pad tokens 49..63 in Vt ----
    for (int idx = lane; idx < 480; idx += 64) {
        int d = idx & 31, t = 49 + (idx >> 5);
        Vt[d * 64 + (((t >> 3) ^ (d & 7)) << 3) + (t & 7)] = 0;
    }
    // ---- stage V rows -> transposed swizzled LDS (wave-local) ----
    for (int idx = lane; idx < 196; idx += 64) {
        int t = idx >> 2, c = idx & 3;
        bf16x8 v = *(const bf16x8*)(QKVb + (size_t)(qbase + t) * 1152 + 768 + head * HD + c * 8);
        int tb = t >> 3, tl = t & 7;
        #pragma unroll
        for (int e = 0; e < 8; ++e) {
            int d = c * 8 + e;
            Vt[d * 64 + ((tb ^ e) << 3) + tl] = (unsigned short)v[e];
        }
    }

    // ---- K/Q fragments straight from global (row-clamped) ----
    bf16x8 kf[4], qf[4];
    #pragma unroll
    for (int t = 0; t < 4; ++t) {
        int rr = t * 16 + l15; if (rr > NTOK - 1) rr = NTOK - 1;
        const unsigned short* base = QKVb + (size_t)(qbase + rr) * 1152 + head * HD + g * 8;
        qf[t] = *(const bf16x8*)base;
        kf[t] = *(const bf16x8*)(base + 384);
    }

    // ---- S^T = K·Q^T + bias (C-init from table) ----
    const float* bb = Bias + (((size_t)wt * HEADS + head) << 12);
    f32x4 acc[4][4];
    #pragma unroll
    for (int jt = 0; jt < 4; ++jt)
        #pragma unroll
        for (int it = 0; it < 4; ++it) {
            f32x4 c = *(const f32x4*)(bb + ((jt * 4 + it) * 64 + lane) * 4);
            acc[jt][it] = __builtin_amdgcn_mfma_f32_16x16x32_bf16(kf[jt], qf[it], c, 0, 0, 0);
        }

    // ---- softmax over j (lane-local per column i), P -> LDS ----
    const float K1 = 0.25503488f;
    #pragma unroll
    for (int jt = 0; jt < 4; ++jt)
        #pragma unroll
        for (int it = 0; it < 4; ++it)
            #pragma unroll
            for (int r = 0; r < 4; ++r)
                acc[jt][it][r] = exp2f(acc[jt][it][r] * K1);

    #pragma unroll
    for (int it = 0; it < 4; ++it) {
        float s = 0.0f;
        #pragma unroll
        for (int jt = 0; jt < 4; ++jt)
            s += (acc[jt][it][0] + acc[jt][it][1]) + (acc[jt][it][2] + acc[jt][it][3]);
        s += __shfl_xor(s, 16);
        s += __shfl_xor(s, 32);
        float inv = 1.0f / s;
        int i  = it * 16 + l15;
        int sw = (i & 7) << 3;
        #pragma unroll
        for (int jt = 0; jt < 4; ++jt) {
            float a0 = acc[jt][it][0] * inv, a1 = acc[jt][it][1] * inv;
            float a2 = acc[jt][it][2] * inv, a3 = acc[jt][it][3] * inv;
            unsigned int w0, w1;
            asm("v_cvt_pk_bf16_f32 %0, %1, %2" : "=v"(w0) : "v"(a0), "v"(a1));
            asm("v_cvt_pk_bf16_f32 %0, %1, %2" : "=v"(w1) : "v"(a2), "v"(a3));
            int js = (jt * 16 + g * 4) ^ sw;
            *(unsigned int*)&Pl[i][js]     = w0;
            *(unsigned int*)&Pl[i][js + 2] = w1;
        }
    }

    // ---- O = P·V ----
    bf16x8 vf[2][2];
    #pragma unroll
    for (int dt = 0; dt < 2; ++dt)
        #pragma unroll
        for (int kc = 0; kc < 2; ++kc) {
            int d = dt * 16 + l15;
            vf[dt][kc] = *(const bf16x8*)&Vt[d * 64 + (((kc * 4 + g) ^ (d & 7)) << 3)];
        }
    f32x4 oacc[4][2];
    #pragma unroll
    for (int it = 0; it < 4; ++it)
        #pragma unroll
        for (int dt = 0; dt < 2; ++dt)
            oacc[it][dt] = (f32x4){0.f, 0.f, 0.f, 0.f};

    #pragma unroll
    for (int it = 0; it < 4; ++it) {
        int i  = it * 16 + l15;
        int sw = (i & 7) << 3;
        #pragma unroll
        for (int kc = 0; kc < 2; ++kc) {
            int js = (kc * 32 + g * 8) ^ sw;
            bf16x8 pf = *(const bf16x8*)&Pl[i][js];
            #pragma unroll
            for (int dt = 0; dt < 2; ++dt)
                oacc[it][dt] = __builtin_amdgcn_mfma_f32_16x16x32_bf16(pf, vf[dt][kc], oacc[it][dt], 0, 0, 0);
        }
    }

    // ---- store O rows (i < 49) ----
    #pragma unroll
    for (int it = 0; it < 4; ++it) {
        #pragma unroll
        for (int r = 0; r < 4; ++r) {
            int i = it * 16 + g * 4 + r;
            if (i < NTOK) {
                unsigned short* orow = outh + (obase + i) * CC + head * HD;
                orow[l15]      = f2bf_fast(oacc[it][0][r]);
                orow[16 + l15] = f2bf_fast(oacc[it][1][r]);
            }
        }
    }
}

// ---------------- launcher ----------------
extern "C" void kernel_launch(void* const* d_in, const int* in_sizes, int n_in,
                              void* d_out, int out_size, void* d_ws, size_t ws_size,
                              hipStream_t stream)
{
    const float* x      = (const float*)d_in[0];
    const float* qkv_w  = (const float*)d_in[2];
    const float* qkv_b  = (const float*)d_in[3];
    const float* proj_w = (const float*)d_in[4];
    const float* proj_b = (const float*)d_in[5];
    const float* rpb    = (const float*)d_in[6];
    const float* n1g    = (const float*)d_in[7];
    const float* n1b    = (const float*)d_in[8];
    const float* n2g    = (const float*)d_in[9];
    const float* n2b    = (const float*)d_in[10];
    const float* fc1w   = (const float*)d_in[11];
    const float* fc1b   = (const float*)d_in[12];
    const float* fc2w   = (const float*)d_in[13];
    const float* fc2b   = (const float*)d_in[14];

    float* xr = (float*)d_out;                     // d_out doubles as xr residual buffer

    // ---- workspace carve-up (hi-only weights) ----
    unsigned short* p = (unsigned short*)d_ws;
    unsigned short* Wqh = p; p += 442368;
    unsigned short* Wph = p; p += 147456;
    unsigned short* W1h = p; p += 589824;
    unsigned short* W2h = p; p += 589824;
    unsigned short* ABh = p; p += (size_t)TOKENS * CC;
    float* Bias = (float*)p;                       // 196608 f32
    unsigned short* region = (unsigned short*)(Bias + 196608);
    unsigned short* Hbuf = region;

    const size_t FIXED = 23592960;                 // bytes before region
    size_t R = (ws_size > FIXED) ? ws_size - FIXED : 0;
    int gq = 2;                                    // images per qkv chunk (bf16: g*3136*1152*2 B)
    if (R >= (size_t)8 * TPI * 1152 * 2)      gq = 8;
    else if (R >= (size_t)4 * TPI * 1152 * 2) gq = 4;
    int gh = 2;                                    // images per MLP chunk (bf16: g*3136*1536*2 B)
    if (R >= (size_t)8 * TPI * HID * 2)      gh = 8;
    else if (R >= (size_t)4 * TPI * HID * 2) gh = 4;

    unsigned short* QKVb = region;                 // [gq*TPI][1152] bf16

    // 0+1. fused prep: bias table + 4 weight transposes + LN1(+shift+window) -> ABh
    prep_all<<<8768, 256, 0, stream>>>(rpb, Bias, qkv_w, Wqh, proj_w, Wph,
                                       fc1w, W1h, fc2w, W2h, x, n1g, n1b, ABh);

    // 2+3. per-chunk: QKV GEMM (128-tile 4-wave depth-2, XCD-swz) -> QKVb, attention -> ABh
    for (int c = 0; c < 8 / gq; ++c) {
        size_t off = (size_t)c * gq * TPI;
        int M = gq * TPI;
        dim3 gmm((3 * CC) / 128, M / 128);
        gemm_mfma<EPI_QKV><<<gmm, 256, 0, stream>>>(
            ABh + off * CC, Wqh, qkv_b, nullptr, nullptr, QKVb, M, 3 * CC, CC);
        attn3<<<gq * NWIN * HEADS / 4, 256, 0, stream>>>(
            QKVb, Bias, ABh, c * gq * NWIN);
    }

    // 4. proj GEMM (128-tile 4-wave depth-2 pipeline, XCD-swz) + window reverse + roll + residual -> xr
    {
        dim3 gmm(CC / 128, TOKENS / 128);
        gemm_mfma<EPI_PROJ><<<gmm, 256, 0, stream>>>(
            ABh, Wph, proj_b, x, xr, nullptr, TOKENS, CC, CC);
    }

    // 5. LN2 -> ABh
    ln2_kernel<<<TOKENS / 4, 256, 0, stream>>>(xr, n2g, n2b, ABh);

    // 6+7. per-chunk: fc1+GELU (128-tile 4-wave) -> Hbuf, fc2 (128-tile 4-wave) + residual -> d_out
    for (int c = 0; c < 8 / gh; ++c) {
        size_t off = (size_t)c * gh * TPI;
        int M = gh * TPI;
        {
            dim3 gmm(HID / 128, M / 128);
            gemm_mfma<EPI_GELU><<<gmm, 256, 0, stream>>>(
                ABh + off * CC, W1h, fc1b, nullptr, nullptr, Hbuf, M, HID, CC);
        }
        {
            dim3 gmm(CC / 128, M / 128);
            gemm_mfma<EPI_FC2><<<gmm, 256, 0, stream>>>(
                Hbuf, W2h, fc2b, xr + off * CC, (float*)d_out + off * CC, nullptr, M, CC, HID);
        }
    }
}

// Round 37
// 200.353 us; speedup vs baseline: 1.0154x; 1.0154x over previous
//
#include <hip/hip_runtime.h>
#include <hip/hip_bf16.h>
#include <math.h>

#define BD 8
#define HH 56
#define WW 56
#define CC 384
#define HEADS 12
#define HD 32
#define WS 7
#define SS 3
#define NTOK 49
#define NWIN 64            // windows per image (8x8)
#define TOKENS (BD*HH*WW)  // 25088
#define HID 1536
#define TPI (HH*WW)        // tokens per image: 3136

typedef __attribute__((ext_vector_type(8))) short bf16x8;
typedef __attribute__((ext_vector_type(4))) float f32x4;

__device__ __forceinline__ unsigned short f2bf(float f) {
    unsigned int u = __float_as_uint(f);
    unsigned int r = (u + 0x7FFFu + ((u >> 16) & 1u)) >> 16;
    return (unsigned short)r;
}
// 1-op RNE f32->bf16 via packed convert (low half); bitwise-identical to f2bf.
__device__ __forceinline__ unsigned short f2bf_fast(float v) {
    unsigned int w;
    asm("v_cvt_pk_bf16_f32 %0, %1, %2" : "=v"(w) : "v"(v), "v"(v));
    return (unsigned short)w;
}
// pack two f32 -> u32 of 2 bf16 (lo = first arg)
__device__ __forceinline__ unsigned int pk2bf(float lo, float hi) {
    unsigned int w;
    asm("v_cvt_pk_bf16_f32 %0, %1, %2" : "=v"(w) : "v"(lo), "v"(hi));
    return w;
}
__device__ __forceinline__ float bf2f(unsigned short h) {
    return __uint_as_float(((unsigned int)h) << 16);
}
__device__ __forceinline__ void gload16(const void* g, void* l) {
    __builtin_amdgcn_global_load_lds((const __attribute__((address_space(1))) unsigned int*)g,
                                     (__attribute__((address_space(3))) unsigned int*)l, 16, 0, 0);
}
// tanh-form GELU via exp2 + hw rcp: ~9 VALU ops, |err vs exact erf-GELU| <= ~3e-4 abs.
__device__ __forceinline__ float fgelu(float x) {
    float x2 = x * x;
    float y  = x * fmaf(0.03567740814f, x2, 0.7978845608f);  // sqrt(2/pi)*(x + 0.044715 x^3)
    float e  = exp2f(y * 2.8853900818f);                     // e^{2y}
    float r  = __builtin_amdgcn_rcpf(e + 1.0f);
    return x - x * r;                                        // 0.5x(1+tanh y)
}
// bijective XCD-aware block swizzle (m204 form)
__device__ __forceinline__ int xcd_swz(int lid, int nwg) {
    int xcd = lid & 7, pos = lid >> 3;
    int q = nwg >> 3, r = nwg & 7;
    return (xcd < r ? xcd * (q + 1) : r * (q + 1) + (xcd - r) * q) + pos;
}

// ---------------- device bodies for the fused prep kernel ----------------
// W[K][N] fp32 -> Wt[N][K] bf16 (32x32 transpose tile)
__device__ __forceinline__ void dev_wprep(const float* __restrict__ W, unsigned short* __restrict__ Th,
                                          int K, int N, int bx, int by, int tid, float (*t)[33])
{
    int n0 = bx * 32, k0 = by * 32;
    int c = tid & 31, r = tid >> 5;   // r: 0..7
    #pragma unroll
    for (int rr = 0; rr < 32; rr += 8)
        t[r + rr][c] = W[(size_t)(k0 + r + rr) * N + n0 + c];
    __syncthreads();
    #pragma unroll
    for (int rr = 0; rr < 32; rr += 8) {
        int i = r + rr;                 // n-local
        Th[(size_t)(n0 + i) * K + k0 + c] = f2bf(t[c][i]);
    }
}

// bias table element e: [4 wtype][12 head][64x64] in MFMA acc layout, pre-scaled
__device__ __forceinline__ void dev_bias(const float* __restrict__ rpb, float* __restrict__ Bias, int e)
{
    int wtq = e / 49152;
    int hr  = e - wtq * 49152;
    int h   = hr >> 12;
    int rem = hr & 4095;
    int jt = rem >> 10, it = (rem >> 8) & 3, lane = (rem >> 2) & 63, reg = rem & 3;
    int j = jt * 16 + ((lane >> 4) << 2) + reg;   // S^T row (= k token)
    int i = it * 16 + (lane & 15);                // S^T col (= q token)
    float val;
    if (j >= NTOK) val = -1e30f;                  // pad columns -> p = 0
    else if (i >= NTOK) val = 0.0f;               // pad q rows, unused
    else {
        int ti = i / 7, tj = i - ti * 7, yj = j / 7, xj = j - yj * 7;
        float b = rpb[((ti - yj + 6) * 13 + (tj - xj + 6)) * HEADS + h];
        int wh7 = wtq >> 1, ww7 = wtq & 1;
        int lhi = wh7 ? (ti < 4 ? 1 : 2) : 0, lhj = wh7 ? (yj < 4 ? 1 : 2) : 0;
        int lwi = ww7 ? (tj < 4 ? 1 : 2) : 0, lwj = ww7 ? (xj < 4 ? 1 : 2) : 0;
        if (lhi != lhj || lwi != lwj) b -= 100.0f;
        val = b * 5.65685424949238f;              // / scale  (scale = 1/sqrt(32))
    }
    Bias[e] = val;
}

// LN row m (shift+window gather), one wave per row: lane owns 6 contiguous elems.
template<bool SHIFT>
__device__ __forceinline__ void dev_ln(const float* __restrict__ in, const float* __restrict__ g,
                                       const float* __restrict__ beta, unsigned short* __restrict__ oh,
                                       int m, int lane)
{
    const float* src;
    size_t dbase = (size_t)m * CC;
    if (SHIFT) {
        int b  = m / (NWIN * NTOK);
        int rr = m % (NWIN * NTOK);
        int w  = rr / NTOK;
        int t  = rr % NTOK;
        int wh = w >> 3, ww = w & 7;
        int ti = t / 7,  tj = t - (t / 7) * 7;
        int hh = wh * WS + ti + SS;  if (hh >= HH) hh -= HH;
        int w2 = ww * WS + tj + SS;  if (w2 >= WW) w2 -= WW;
        src = in + ((size_t)b * TPI + hh * WW + w2) * CC;
    } else {
        src = in + (size_t)m * CC;
    }
    int e0 = lane * 6;
    float2 a  = *(const float2*)(src + e0);
    float2 b2 = *(const float2*)(src + e0 + 2);
    float2 c2 = *(const float2*)(src + e0 + 4);
    float s  = (a.x + a.y) + (b2.x + b2.y) + (c2.x + c2.y);
    float ss = a.x*a.x + a.y*a.y + b2.x*b2.x + b2.y*b2.y + c2.x*c2.x + c2.y*c2.y;
    #pragma unroll
    for (int off = 1; off < 64; off <<= 1) {
        s  += __shfl_xor(s, off);
        ss += __shfl_xor(ss, off);
    }
    float mu   = s * (1.0f / CC);
    float var  = ss * (1.0f / CC) - mu * mu;
    float rstd = rsqrtf(var + 1e-5f);
    float2 ga = *(const float2*)(g + e0);
    float2 gb = *(const float2*)(g + e0 + 2);
    float2 gc = *(const float2*)(g + e0 + 4);
    float2 ba = *(const float2*)(beta + e0);
    float2 bb = *(const float2*)(beta + e0 + 2);
    float2 bc = *(const float2*)(beta + e0 + 4);
    float y0 = (a.x  - mu) * rstd * ga.x + ba.x;
    float y1 = (a.y  - mu) * rstd * ga.y + ba.y;
    float y2 = (b2.x - mu) * rstd * gb.x + bb.x;
    float y3 = (b2.y - mu) * rstd * gb.y + bb.y;
    float y4 = (c2.x - mu) * rstd * gc.x + bc.x;
    float y5 = (c2.y - mu) * rstd * gc.y + bc.y;
    unsigned short* orow = oh + dbase + e0;
    *(unsigned int*)(orow)     = pk2bf(y0, y1);
    *(unsigned int*)(orow + 2) = pk2bf(y2, y3);
    *(unsigned int*)(orow + 4) = pk2bf(y4, y5);
}

// ---------------- fused prep: bias table + 4 weight transposes + LN1 (all independent) ------
// blocks [0,768) bias | [768,1200) Wq | [1200,1344) Wp | [1344,1920) W1 | [1920,2496) W2 |
// [2496,8768) LN1 (4 rows/block)
__global__ __launch_bounds__(256)
void prep_all(const float* __restrict__ rpb, float* __restrict__ Bias,
              const float* __restrict__ qkv_w, unsigned short* __restrict__ Wqh,
              const float* __restrict__ proj_w, unsigned short* __restrict__ Wph,
              const float* __restrict__ fc1w, unsigned short* __restrict__ W1h,
              const float* __restrict__ fc2w, unsigned short* __restrict__ W2h,
              const float* __restrict__ x, const float* __restrict__ n1g,
              const float* __restrict__ n1b, unsigned short* __restrict__ ABh)
{
    __shared__ float t[32][33];
    int b = blockIdx.x, tid = threadIdx.x;
    if (b < 768) {
        dev_bias(rpb, Bias, b * 256 + tid);
    } else if (b < 1200) {
        int id = b - 768;  dev_wprep(qkv_w,  Wqh, 384, 1152, id % 36, id / 36, tid, t);
    } else if (b < 1344) {
        int id = b - 1200; dev_wprep(proj_w, Wph, 384,  384, id % 12, id / 12, tid, t);
    } else if (b < 1920) {
        int id = b - 1344; dev_wprep(fc1w,   W1h, 384, 1536, id % 48, id / 48, tid, t);
    } else if (b < 2496) {
        int id = b - 1920; dev_wprep(fc2w,   W2h, 1536, 384, id % 12, id / 12, tid, t);
    } else {
        int m = (b - 2496) * 4 + (tid >> 6);
        dev_ln<true>(x, n1g, n1b, ABh, m, tid & 63);
    }
}

// ---------------- standalone LN (ln2, no shift): 1 wave/row, 4 rows/block ----------------
__global__ __launch_bounds__(256)
void ln2_kernel(const float* __restrict__ in, const float* __restrict__ g,
                const float* __restrict__ beta, unsigned short* __restrict__ oh)
{
    int m = blockIdx.x * 4 + (threadIdx.x >> 6);
    dev_ln<false>(in, g, beta, oh, m, threadIdx.x & 63);
}

// ================ epilogue types ================
#define EPI_QKV  0   // outh = bf16(acc + bias)  -> QKVb [tok][1152] coalesced
#define EPI_GELU 1   // outh = bf16(gelu(acc + bias))           (fc1)
#define EPI_PROJ 2   // outf[pix] = extra[pix] + acc + bias     (proj + window-reverse + roll + residual)
#define EPI_FC2  3   // outf = extra + acc + bias               (fc2 + residual)

// ---------------- 1-pass bf16 MFMA GEMM: 128x128 tile, BK=32, 4 WAVES x (64x64 each) -------
// m97 shape: per-wave 64x64 -> 32.8 FLOP per LDS-read-byte; VALUBusy ~12% (r35 measured).
// 3-buffer, prefetch-distance-2 counted-vmcnt pipeline (validated r26/r27), scaled to
// 4 loads/wave/tile -> steady vmcnt(8), tails 4/0. LDS 48 KB -> 3 blocks x 4 waves = 12 w/CU.
#define COMPUTE128(B) do {                                                          \
    bf16x8 ah[4], bh[4];                                                            \
    _Pragma("unroll")                                                               \
    for (int f = 0; f < 4; ++f) {                                                   \
        int row = wr * 64 + f * 16 + rA;                                            \
        int pp = (kslot ^ ((row >> 1) & 3)) * 8;                                    \
        ah[f] = *(const bf16x8*)&lds[B][0][row][pp];                                \
        int col = wc * 64 + f * 16 + rA;                                            \
        int pb = (kslot ^ ((col >> 1) & 3)) * 8;                                    \
        bh[f] = *(const bf16x8*)&lds[B][1][col][pb];                                \
    }                                                                               \
    _Pragma("unroll")                                                               \
    for (int i = 0; i < 4; ++i)                                                     \
        _Pragma("unroll")                                                           \
        for (int j = 0; j < 4; ++j)                                                 \
            acc[i][j] = __builtin_amdgcn_mfma_f32_16x16x32_bf16(ah[i], bh[j], acc[i][j], 0, 0, 0); \
} while (0)

template<int EPI>
__global__ __launch_bounds__(256)
void gemm_mfma(const unsigned short* __restrict__ Ah, const unsigned short* __restrict__ Bh,
               const float* __restrict__ bias, const float* __restrict__ extra,
               float* __restrict__ outf, unsigned short* __restrict__ outh,
               int M, int N, int K)
{
    __shared__ unsigned short lds[3][2][128][32];   // [buf][A/B][row][k], 48 KB

    int nwg = gridDim.x * gridDim.y;
    int wid = xcd_swz(blockIdx.y * gridDim.x + blockIdx.x, nwg);
    int nblk = wid % gridDim.x;
    int mblk = wid / gridDim.x;

    int tid  = threadIdx.x;
    int lane = tid & 63;
    int wave = tid >> 6;       // 0..3
    int wr = wave >> 1;        // 0..1 (M half)
    int wc = wave & 1;         // 0..1 (N half)
    int m0 = mblk * 128, n0 = nblk * 128;

    int lrow = lane >> 2;      // staging row within 16-row chunk
    int ps   = lane & 3;       // staging 16B slot
    int kslot = lane >> 4;     // frag k-chunk
    int rA    = lane & 15;     // frag row/col

    // hoisted loop-invariant staging addresses (4 segs, 3 buffer dests each)
    const unsigned short* gsrc[4];
    unsigned short* d0[4];
    unsigned short* d1[4];
    unsigned short* d2[4];
    #pragma unroll
    for (int s = 0; s < 4; ++s) {
        int seg = wave * 4 + s;          // 0..15: 0-7 A, 8-15 Bh
        int bf = seg >> 3, c = seg & 7;
        const unsigned short* gb = (bf == 0) ? Ah : Bh;
        int r0 = (bf == 0) ? m0 : n0;
        int row = c * 16 + lrow;
        int ks = ps ^ ((row >> 1) & 3);
        gsrc[s] = gb + (size_t)(r0 + row) * K + ks * 8;
        d0[s] = &lds[0][bf][c * 16][0];
        d1[s] = &lds[1][bf][c * 16][0];
        d2[s] = &lds[2][bf][c * 16][0];
    }

    f32x4 acc[4][4];
    #pragma unroll
    for (int i = 0; i < 4; ++i)
        #pragma unroll
        for (int j = 0; j < 4; ++j)
            acc[i][j] = (f32x4){0.f, 0.f, 0.f, 0.f};

    const int nt = K / 32;     // 12 (proj) or 48 (fc2); both % 3 == 0
    // prologue: tiles 0,1 -> buf0,buf1 (8 loads outstanding)
    #pragma unroll
    for (int s = 0; s < 4; ++s) gload16(gsrc[s], d0[s]);
    #pragma unroll
    for (int s = 0; s < 4; ++s) gload16(gsrc[s] + 32, d1[s]);
    for (int t = 0; t < nt; t += 3) {
        // phase A: prefetch t+2 -> buf2, wait tile t, compute buf0
        if (t + 2 < nt) {
            int ka = (t + 2) * 32;
            #pragma unroll
            for (int s = 0; s < 4; ++s) gload16(gsrc[s] + ka, d2[s]);
            asm volatile("s_waitcnt vmcnt(8)" ::: "memory");
        } else if (t + 1 < nt) {
            asm volatile("s_waitcnt vmcnt(4)" ::: "memory");
        } else {
            asm volatile("s_waitcnt vmcnt(0)" ::: "memory");
        }
        __builtin_amdgcn_sched_barrier(0);
        __builtin_amdgcn_s_barrier();
        __builtin_amdgcn_sched_barrier(0);
        COMPUTE128(0);
        __builtin_amdgcn_s_barrier();
        // phase B: prefetch t+3 -> buf0, wait tile t+1, compute buf1
        if (t + 3 < nt) {
            int kb = (t + 3) * 32;
            #pragma unroll
            for (int s = 0; s < 4; ++s) gload16(gsrc[s] + kb, d0[s]);
            asm volatile("s_waitcnt vmcnt(8)" ::: "memory");
        } else if (t + 2 < nt) {
            asm volatile("s_waitcnt vmcnt(4)" ::: "memory");
        } else {
            asm volatile("s_waitcnt vmcnt(0)" ::: "memory");
        }
        __builtin_amdgcn_sched_barrier(0);
        __builtin_amdgcn_s_barrier();
        __builtin_amdgcn_sched_barrier(0);
        COMPUTE128(1);
        __builtin_amdgcn_s_barrier();
        // phase C: prefetch t+4 -> buf1, wait tile t+2, compute buf2
        if (t + 4 < nt) {
            int kc = (t + 4) * 32;
            #pragma unroll
            for (int s = 0; s < 4; ++s) gload16(gsrc[s] + kc, d1[s]);
            asm volatile("s_waitcnt vmcnt(8)" ::: "memory");
        } else if (t + 3 < nt) {
            asm volatile("s_waitcnt vmcnt(4)" ::: "memory");
        } else {
            asm volatile("s_waitcnt vmcnt(0)" ::: "memory");
        }
        __builtin_amdgcn_sched_barrier(0);
        __builtin_amdgcn_s_barrier();
        __builtin_amdgcn_sched_barrier(0);
        COMPUTE128(2);
        __builtin_amdgcn_s_barrier();
    }

    int cn = lane & 15;
    int rb = (lane >> 4) * 4;
    float bj[4];
    #pragma unroll
    for (int j = 0; j < 4; ++j) bj[j] = bias[n0 + wc * 64 + j * 16 + cn];
    int ncol = n0 + wc * 64 + cn;

    #pragma unroll
    for (int i = 0; i < 4; ++i) {
        #pragma unroll
        for (int r = 0; r < 4; ++r) {
            int mg = m0 + wr * 64 + i * 16 + rb + r;
            if (EPI == EPI_PROJ) {
                int b  = mg / (NWIN * NTOK);
                int rr = mg % (NWIN * NTOK);
                int w  = rr / NTOK;
                int t  = rr % NTOK;
                int wh = w >> 3, ww = w & 7;
                int ti = t / 7,  tj = t - (t / 7) * 7;
                int hh = wh * WS + ti + SS;  if (hh >= HH) hh -= HH;
                int w2 = ww * WS + tj + SS;  if (w2 >= WW) w2 -= WW;
                size_t pix = (size_t)b * TPI + hh * WW + w2;
                const float* xin = extra + pix * CC + ncol;
                float* xo = outf + pix * CC + ncol;
                #pragma unroll
                for (int j = 0; j < 4; ++j) xo[j * 16] = xin[j * 16] + acc[i][j][r] + bj[j];
            } else { // EPI_FC2
                const float* xi = extra + (size_t)mg * N + ncol;
                float* xo = outf + (size_t)mg * N + ncol;
                #pragma unroll
                for (int j = 0; j < 4; ++j) xo[j * 16] = xi[j * 16] + acc[i][j][r] + bj[j];
            }
        }
    }
}

// ------- BM=256 x BN=128, 8 waves, 1-pass, BK=32 2-phase counted-vmcnt, XCD-swz (qkv/fc1) -------
// Per-wave loads/tile = 3 -> vmcnt(3); tail: vmcnt(0).  (validated r26/r27)
#define COMPUTE256(B) do {                                                          \
    bf16x8 ah[4], bh[4];                                                            \
    _Pragma("unroll")                                                               \
    for (int f = 0; f < 4; ++f) {                                                   \
        int row = wr * 64 + f * 16 + rA;                                            \
        int pp = (kslot ^ ((row >> 1) & 3)) * 8;                                    \
        ah[f] = *(const bf16x8*)&ldsA[B][row][pp];                                  \
        int col = wc * 64 + f * 16 + rA;                                            \
        int pb = (kslot ^ ((col >> 1) & 3)) * 8;                                    \
        bh[f] = *(const bf16x8*)&ldsB[B][col][pb];                                  \
    }                                                                               \
    _Pragma("unroll")                                                               \
    for (int i = 0; i < 4; ++i)                                                     \
        _Pragma("unroll")                                                           \
        for (int j = 0; j < 4; ++j)                                                 \
            acc[i][j] = __builtin_amdgcn_mfma_f32_16x16x32_bf16(ah[i], bh[j], acc[i][j], 0, 0, 0); \
} while (0)

template<int EPI>
__global__ __launch_bounds__(512)
void gemm_mfma256(const unsigned short* __restrict__ Ah, const unsigned short* __restrict__ Bh,
                  const float* __restrict__ bias,
                  float* __restrict__ outf, unsigned short* __restrict__ outh,
                  int M, int N, int K)
{
    __shared__ unsigned short ldsA[2][256][32];
    __shared__ unsigned short ldsB[2][128][32];

    int nwg = gridDim.x * gridDim.y;
    int wid = xcd_swz(blockIdx.y * gridDim.x + blockIdx.x, nwg);
    int nblk = wid % gridDim.x;
    int mblk = wid / gridDim.x;

    int tid  = threadIdx.x;
    int lane = tid & 63;
    int wave = tid >> 6;             // 0..7
    int wr = wave >> 1;              // 0..3  (M quadrant)
    int wc = wave & 1;               // 0..1  (N half)
    int m0 = mblk * 256, n0 = nblk * 128;

    int lrow = lane >> 2;
    int ps   = lane & 3;
    int kslot = lane >> 4;
    int rA    = lane & 15;

    // hoisted loop-invariant staging addresses (3 segs, 2 buffer dests each)
    const unsigned short* gsrc[3];
    unsigned short* d0[3];
    unsigned short* d1[3];
    #pragma unroll
    for (int s = 0; s < 3; ++s) {
        int seg = wave * 3 + s;          // 0..23: 0-15 A, 16-23 Bh
        const unsigned short* gb;
        unsigned short *l0, *l1;
        int c, r0;
        if (seg < 16) { gb = Ah; c = seg;      r0 = m0; l0 = &ldsA[0][c * 16][0]; l1 = &ldsA[1][c * 16][0]; }
        else          { gb = Bh; c = seg - 16; r0 = n0; l0 = &ldsB[0][c * 16][0]; l1 = &ldsB[1][c * 16][0]; }
        int row = c * 16 + lrow;
        int ks = ps ^ ((row >> 1) & 3);
        gsrc[s] = gb + (size_t)(r0 + row) * K + ks * 8;
        d0[s] = l0; d1[s] = l1;
    }

    f32x4 acc[4][4];
    #pragma unroll
    for (int i = 0; i < 4; ++i)
        #pragma unroll
        for (int j = 0; j < 4; ++j)
            acc[i][j] = (f32x4){0.f, 0.f, 0.f, 0.f};

    const int nt = K / 32;           // 12 for K=384 (even)
    // prologue: tile 0 -> buf0 (3 loads in flight)
    #pragma unroll
    for (int s = 0; s < 3; ++s) gload16(gsrc[s], d0[s]);
    for (int t = 0; t < nt; t += 2) {
        {
            int k1 = (t + 1) * 32;
            #pragma unroll
            for (int s = 0; s < 3; ++s) gload16(gsrc[s] + k1, d1[s]);
        }
        asm volatile("s_waitcnt vmcnt(3)" ::: "memory");
        __builtin_amdgcn_sched_barrier(0);
        __builtin_amdgcn_s_barrier();
        __builtin_amdgcn_sched_barrier(0);
        COMPUTE256(0);
        __builtin_amdgcn_s_barrier();
        if (t + 2 < nt) {
            int k2 = (t + 2) * 32;
            #pragma unroll
            for (int s = 0; s < 3; ++s) gload16(gsrc[s] + k2, d0[s]);
            asm volatile("s_waitcnt vmcnt(3)" ::: "memory");
        } else {
            asm volatile("s_waitcnt vmcnt(0)" ::: "memory");
        }
        __builtin_amdgcn_sched_barrier(0);
        __builtin_amdgcn_s_barrier();
        __builtin_amdgcn_sched_barrier(0);
        COMPUTE256(1);
        __builtin_amdgcn_s_barrier();
    }

    int cn = lane & 15;
    int rb = (lane >> 4) * 4;
    float bj[4];
    #pragma unroll
    for (int j = 0; j < 4; ++j) bj[j] = bias[n0 + wc * 64 + j * 16 + cn];
    int ncol = n0 + wc * 64 + cn;

    #pragma unroll
    for (int i = 0; i < 4; ++i) {
        #pragma unroll
        for (int r = 0; r < 4; ++r) {
            int mg = m0 + wr * 64 + i * 16 + rb + r;
            if (EPI == EPI_QKV) {
                unsigned short* orow = outh + (size_t)mg * N + ncol;
                #pragma unroll
                for (int j = 0; j < 4; ++j) orow[j * 16] = f2bf_fast(acc[i][j][r] + bj[j]);
            } else { // EPI_GELU
                unsigned short* orow = outh + (size_t)mg * N + ncol;
                #pragma unroll
                for (int j = 0; j < 4; ++j)
                    orow[j * 16] = f2bf_fast(fgelu(acc[i][j][r] + bj[j]));
            }
        }
    }
}

// ---------------- Attention v4: MFMA, one wave per (window, head), LDS V-transpose ----------
__global__ __launch_bounds__(256)
void attn3(const unsigned short* __restrict__ QKVb, const float* __restrict__ Bias,
           unsigned short* __restrict__ outh, int win0)
{
    int wave = threadIdx.x >> 6, lane = threadIdx.x & 63;
    int unit = blockIdx.x * 4 + wave;
    int head = unit % HEADS;
    int winl = unit / HEADS;
    int wing = win0 + winl;
    int wl   = wing & (NWIN - 1);
    int wt   = (((wl >> 3) == 7) << 1) | ((wl & 7) == 7);
    int qbase = winl * NTOK;
    size_t obase = (size_t)wing * NTOK;

    __shared__ __align__(16) unsigned short Pl_all[4][64][64];
    __shared__ __align__(16) unsigned short Vt_all[4][2048];   // [32 d][8 blk of 8 tok], XOR-swizzled
    unsigned short (*Pl)[64] = Pl_all[wave];
    unsigned short* Vt = Vt_all[wave];

    int l15 = lane & 15, g = lane >> 4;

    // ---- zero pad tokens 49..63 in Vt ----
    for (int idx = lane; idx < 480; idx += 64) {
        int d = idx & 31, t = 49 + (idx >> 5);
        Vt[d * 64 + (((t >> 3) ^ (d & 7)) << 3) + (t & 7)] = 0;
    }
    // ---- stage V rows -> transposed swizzled LDS (wave-local) ----
    for (int idx = lane; idx < 196; idx += 64) {
        int t = idx >> 2, c = idx & 3;
        bf16x8 v = *(const bf16x8*)(QKVb + (size_t)(qbase + t) * 1152 + 768 + head * HD + c * 8);
        int tb = t >> 3, tl = t & 7;
        #pragma unroll
        for (int e = 0; e < 8; ++e) {
            int d = c * 8 + e;
            Vt[d * 64 + ((tb ^ e) << 3) + tl] = (unsigned short)v[e];
        }
    }

    // ---- K/Q fragments straight from global (row-clamped) ----
    bf16x8 kf[4], qf[4];
    #pragma unroll
    for (int t = 0; t < 4; ++t) {
        int rr = t * 16 + l15; if (rr > NTOK - 1) rr = NTOK - 1;
        const unsigned short* base = QKVb + (size_t)(qbase + rr) * 1152 + head * HD + g * 8;
        qf[t] = *(const bf16x8*)base;
        kf[t] = *(const bf16x8*)(base + 384);
    }

    // ---- S^T = K·Q^T + bias (C-init from table) ----
    const float* bb = Bias + (((size_t)wt * HEADS + head) << 12);
    f32x4 acc[4][4];
    #pragma unroll
    for (int jt = 0; jt < 4; ++jt)
        #pragma unroll
        for (int it = 0; it < 4; ++it) {
            f32x4 c = *(const f32x4*)(bb + ((jt * 4 + it) * 64 + lane) * 4);
            acc[jt][it] = __builtin_amdgcn_mfma_f32_16x16x32_bf16(kf[jt], qf[it], c, 0, 0, 0);
        }

    // ---- softmax over j (lane-local per column i), P -> LDS ----
    const float K1 = 0.25503488f;
    #pragma unroll
    for (int jt = 0; jt < 4; ++jt)
        #pragma unroll
        for (int it = 0; it < 4; ++it)
            #pragma unroll
            for (int r = 0; r < 4; ++r)
                acc[jt][it][r] = exp2f(acc[jt][it][r] * K1);

    #pragma unroll
    for (int it = 0; it < 4; ++it) {
        float s = 0.0f;
        #pragma unroll
        for (int jt = 0; jt < 4; ++jt)
            s += (acc[jt][it][0] + acc[jt][it][1]) + (acc[jt][it][2] + acc[jt][it][3]);
        s += __shfl_xor(s, 16);
        s += __shfl_xor(s, 32);
        float inv = 1.0f / s;
        int i  = it * 16 + l15;
        int sw = (i & 7) << 3;
        #pragma unroll
        for (int jt = 0; jt < 4; ++jt) {
            float a0 = acc[jt][it][0] * inv, a1 = acc[jt][it][1] * inv;
            float a2 = acc[jt][it][2] * inv, a3 = acc[jt][it][3] * inv;
            unsigned int w0, w1;
            asm("v_cvt_pk_bf16_f32 %0, %1, %2" : "=v"(w0) : "v"(a0), "v"(a1));
            asm("v_cvt_pk_bf16_f32 %0, %1, %2" : "=v"(w1) : "v"(a2), "v"(a3));
            int js = (jt * 16 + g * 4) ^ sw;
            *(unsigned int*)&Pl[i][js]     = w0;
            *(unsigned int*)&Pl[i][js + 2] = w1;
        }
    }

    // ---- O = P·V ----
    bf16x8 vf[2][2];
    #pragma unroll
    for (int dt = 0; dt < 2; ++dt)
        #pragma unroll
        for (int kc = 0; kc < 2; ++kc) {
            int d = dt * 16 + l15;
            vf[dt][kc] = *(const bf16x8*)&Vt[d * 64 + (((kc * 4 + g) ^ (d & 7)) << 3)];
        }
    f32x4 oacc[4][2];
    #pragma unroll
    for (int it = 0; it < 4; ++it)
        #pragma unroll
        for (int dt = 0; dt < 2; ++dt)
            oacc[it][dt] = (f32x4){0.f, 0.f, 0.f, 0.f};

    #pragma unroll
    for (int it = 0; it < 4; ++it) {
        int i  = it * 16 + l15;
        int sw = (i & 7) << 3;
        #pragma unroll
        for (int kc = 0; kc < 2; ++kc) {
            int js = (kc * 32 + g * 8) ^ sw;
            bf16x8 pf = *(const bf16x8*)&Pl[i][js];
            #pragma unroll
            for (int dt = 0; dt < 2; ++dt)
                oacc[it][dt] = __builtin_amdgcn_mfma_f32_16x16x32_bf16(pf, vf[dt][kc], oacc[it][dt], 0, 0, 0);
        }
    }

    // ---- store O rows (i < 49) ----
    #pragma unroll
    for (int it = 0; it < 4; ++it) {
        #pragma unroll
        for (int r = 0; r < 4; ++r) {
            int i = it * 16 + g * 4 + r;
            if (i < NTOK) {
                unsigned short* orow = outh + (obase + i) * CC + head * HD;
                orow[l15]      = f2bf_fast(oacc[it][0][r]);
                orow[16 + l15] = f2bf_fast(oacc[it][1][r]);
            }
        }
    }
}

// ---------------- launcher ----------------
extern "C" void kernel_launch(void* const* d_in, const int* in_sizes, int n_in,
                              void* d_out, int out_size, void* d_ws, size_t ws_size,
                              hipStream_t stream)
{
    const float* x      = (const float*)d_in[0];
    const float* qkv_w  = (const float*)d_in[2];
    const float* qkv_b  = (const float*)d_in[3];
    const float* proj_w = (const float*)d_in[4];
    const float* proj_b = (const float*)d_in[5];
    const float* rpb    = (const float*)d_in[6];
    const float* n1g    = (const float*)d_in[7];
    const float* n1b    = (const float*)d_in[8];
    const float* n2g    = (const float*)d_in[9];
    const float* n2b    = (const float*)d_in[10];
    const float* fc1w   = (const float*)d_in[11];
    const float* fc1b   = (const float*)d_in[12];
    const float* fc2w   = (const float*)d_in[13];
    const float* fc2b   = (const float*)d_in[14];

    float* xr = (float*)d_out;                     // d_out doubles as xr residual buffer

    // ---- workspace carve-up (hi-only weights) ----
    unsigned short* p = (unsigned short*)d_ws;
    unsigned short* Wqh = p; p += 442368;
    unsigned short* Wph = p; p += 147456;
    unsigned short* W1h = p; p += 589824;
    unsigned short* W2h = p; p += 589824;
    unsigned short* ABh = p; p += (size_t)TOKENS * CC;
    float* Bias = (float*)p;                       // 196608 f32
    unsigned short* region = (unsigned short*)(Bias + 196608);
    unsigned short* Hbuf = region;

    const size_t FIXED = 23592960;                 // bytes before region
    size_t R = (ws_size > FIXED) ? ws_size - FIXED : 0;
    int gq = 2;                                    // images per qkv chunk (bf16: g*3136*1152*2 B)
    if (R >= (size_t)8 * TPI * 1152 * 2)      gq = 8;
    else if (R >= (size_t)4 * TPI * 1152 * 2) gq = 4;
    int gh = 2;                                    // images per MLP chunk (bf16: g*3136*1536*2 B)
    if (R >= (size_t)8 * TPI * HID * 2)      gh = 8;
    else if (R >= (size_t)4 * TPI * HID * 2) gh = 4;

    unsigned short* QKVb = region;                 // [gq*TPI][1152] bf16

    // 0+1. fused prep: bias table + 4 weight transposes + LN1(+shift+window) -> ABh
    prep_all<<<8768, 256, 0, stream>>>(rpb, Bias, qkv_w, Wqh, proj_w, Wph,
                                       fc1w, W1h, fc2w, W2h, x, n1g, n1b, ABh);

    // 2+3. per-chunk: QKV GEMM (256-tile, counted-vmcnt pipeline, XCD-swz) -> QKVb, attention -> ABh
    for (int c = 0; c < 8 / gq; ++c) {
        size_t off = (size_t)c * gq * TPI;
        int M = gq * TPI;
        dim3 gmm((3 * CC) / 128, M / 256);
        gemm_mfma256<EPI_QKV><<<gmm, 512, 0, stream>>>(
            ABh + off * CC, Wqh, qkv_b, nullptr, QKVb, M, 3 * CC, CC);
        attn3<<<gq * NWIN * HEADS / 4, 256, 0, stream>>>(
            QKVb, Bias, ABh, c * gq * NWIN);
    }

    // 4. proj GEMM (128-tile 4-wave depth-2 pipeline, XCD-swz) + window reverse + roll + residual -> xr
    {
        dim3 gmm(CC / 128, TOKENS / 128);
        gemm_mfma<EPI_PROJ><<<gmm, 256, 0, stream>>>(
            ABh, Wph, proj_b, x, xr, nullptr, TOKENS, CC, CC);
    }

    // 5. LN2 -> ABh
    ln2_kernel<<<TOKENS / 4, 256, 0, stream>>>(xr, n2g, n2b, ABh);

    // 6+7. per-chunk: fc1+GELU (256-tile pipeline) -> Hbuf, fc2 (128-tile 4-wave depth-2) + residual -> d_out
    for (int c = 0; c < 8 / gh; ++c) {
        size_t off = (size_t)c * gh * TPI;
        int M = gh * TPI;
        {
            dim3 gmm(HID / 128, M / 256);
            gemm_mfma256<EPI_GELU><<<gmm, 512, 0, stream>>>(
                ABh + off * CC, W1h, fc1b, nullptr, Hbuf, M, HID, CC);
        }
        {
            dim3 gmm(CC / 128, M / 128);
            gemm_mfma<EPI_FC2><<<gmm, 256, 0, stream>>>(
                Hbuf, W2h, fc2b, xr + off * CC, (float*)d_out + off * CC, nullptr, M, CC, HID);
        }
    }
}